// Round 5
// baseline (136.529 us; speedup 1.0000x reference)
//
#include <hip/hip_runtime.h>
#include <hip/hip_fp16.h>

// Problem constants
#define OOv   200
#define KKv   1600
#define OPAD  208              // 13 col-tiles of 16
#define NSTEPS 50              // K=32 MFMA steps
#define NSUPER 25              // BK=64 super-steps
#define CHUNK_BYTES 13312      // full-width K=32 chunk of W-fp16 (208*4 slots *16B)
#define HALF0_BYTES 7168       // cols 0..111   (7 tiles) within a chunk
#define XSTR 40                // halfs per x row in LDS (80 B)
#define YSTR 40                // halfs per y row in LDS (80 B)

typedef _Float16 half8  __attribute__((ext_vector_type(8)));
typedef _Float16 half2v __attribute__((ext_vector_type(2)));
typedef __attribute__((ext_vector_type(4))) float floatx4;

// ---------------------------------------------------------------------------
// Pre-kernel: W [200][1600] fp32 -> Wh fp16, PERMUTED-K chunk-major, swizzled.
// Wh idx = t*6656 + slot*8 + j ; slot = o*4 + (kg ^ ((o>>1)&3)) ;
// k_orig = (4*(t/5) + kg)*40 + 8*(t%5) + j     <-- the K-permutation
// With this ordering, at step t every lane's y-window is m in [8*(t%5), +8)
// (uniform across lanes) and x-index n = 4*(t/5)+kg (changes once per 5 steps).
// ---------------------------------------------------------------------------
__global__ void wb_convert_kernel(const float* __restrict__ W,
                                  unsigned short* __restrict__ Wh) {
    int idx = blockIdx.x * 256 + threadIdx.x;
    if (idx >= NSTEPS * OPAD * 32) return;      // 332800
    int j    = idx & 7;
    int slot = (idx >> 3) % (OPAD * 4);
    int t    = (idx >> 3) / (OPAD * 4);
    int o    = slot >> 2;
    int kgs  = slot & 3;
    int kg   = kgs ^ ((o >> 1) & 3);
    int k    = (4 * (t / 5) + kg) * 40 + 8 * (t % 5) + j;
    float v  = (o < OOv) ? W[o * KKv + k] : 0.0f;
    union { _Float16 h; unsigned short u; } cv; cv.h = (_Float16)v;
    Wh[idx] = cv.u;
}

// ---------------------------------------------------------------------------
// Main kernel: 1024 blocks x 256 thr. Block = 128 rows x colhalf (112 or 96).
//   ch = blockIdx&1: ch0 -> cols 0..111 (7 tiles), ch1 -> cols 112..207 (6).
// Waves: rowhalf = wave&1 (rt=4), colgrp = wave>>1 (ct 4/3 within the half).
// y lives ENTIRELY in registers (80 VGPR/lane); K-loop LDS = B-frags only.
// acc <= 64; 25 super-step barriers; global_load_lds(16B) B staging.
// ---------------------------------------------------------------------------
__global__ __launch_bounds__(256, 2) void cin_mfma_kernel(
        const float* __restrict__ X, const float* __restrict__ Y,
        const unsigned short* __restrict__ Wh, float* __restrict__ Out) {
    __shared__ __align__(16) unsigned char bsm[2 * HALF0_BYTES * 2]; // 28672
    __shared__ __align__(16) _Float16 xlds[128 * XSTR];              // 10240
    __shared__ __align__(16) _Float16 ylds[128 * YSTR];              // 10240

    const int tid     = threadIdx.x;
    const int wave    = tid >> 6;
    const int lane    = tid & 63;
    const int li      = lane & 15;
    const int kg      = lane >> 4;
    const int rowhalf = wave & 1;
    const int colgrp  = wave >> 1;

    const int ch      = blockIdx.x & 1;
    const long blockbase = (long)(blockIdx.x >> 1) * 128;
    const int htiles  = ch ? 6 : 7;              // tiles in this col-half
    const int ntiles  = colgrp ? htiles - 4 : 4; // 4 / 3(or 2? no: 7->4+3, 6->4+2? )
    // 7 tiles -> {4,3}; 6 tiles -> {4,2}? prefer {3,3} for 6: balance below
    const int nt      = ch ? (colgrp ? 3 : 3) : (colgrp ? 3 : 4);
    const int cbt     = ch ? (colgrp ? 3 : 0) : (colgrp ? 4 : 0); // first tile idx
    const int half_bytes = ch ? 6144 : 7168;     // staged bytes per chunk

    // ---- prologue: stage x,y (128 rows x 40) as fp16 into LDS
    const float* xg = X + blockbase * 40;
    const float* yg = Y + blockbase * 40;
    for (int i = tid; i < 1280; i += 256) {
        int r  = i / 10;
        int c4 = (i % 10) * 4;                   // 40 % 4 == 0: row-aligned
        floatx4 vx = *(const floatx4*)(xg + i * 4);
        floatx4 vy = *(const floatx4*)(yg + i * 4);
        union { half2v h[2]; unsigned long long u; } px, py;
        px.h[0] = (half2v){(_Float16)vx.x, (_Float16)vx.y};
        px.h[1] = (half2v){(_Float16)vx.z, (_Float16)vx.w};
        py.h[0] = (half2v){(_Float16)vy.x, (_Float16)vy.y};
        py.h[1] = (half2v){(_Float16)vy.z, (_Float16)vy.w};
        *(unsigned long long*)(xlds + r * XSTR + c4) = px.u;
        *(unsigned long long*)(ylds + r * YSTR + c4) = py.u;
    }
    // stage super-chunk 0 (chunks t=0,1, this col-half only)
    {
        const char* src0 = (const char*)Wh + ch * HALF0_BYTES;
        for (int q = 0; q < 2; ++q) {
            const char* src = src0 + (size_t)q * CHUNK_BYTES;
            unsigned char* dst = bsm + q * HALF0_BYTES;
            for (int u = wave; u * 1024 < half_bytes; u += 4) {
                int off = u * 1024 + lane * 16;
                if (off < half_bytes)
                    __builtin_amdgcn_global_load_lds(
                        (const __attribute__((address_space(1))) unsigned int*)(src + off),
                        (__attribute__((address_space(3))) unsigned int*)(dst + off),
                        16, 0, 0);
            }
        }
    }
    __syncthreads();

    // ---- y rows into registers: yr[rt][grp] = y[row][8*grp .. 8*grp+7]
    const int rowb = rowhalf * 64 + li;
    half8 yr[4][5];
#pragma unroll
    for (int rt = 0; rt < 4; ++rt) {
        int row = rowb + rt * 16;
#pragma unroll
        for (int grp = 0; grp < 5; ++grp)
            yr[rt][grp] = *(const half8*)(ylds + row * YSTR + grp * 8);
    }

    floatx4 acc[4][4];
#pragma unroll
    for (int rt = 0; rt < 4; ++rt)
#pragma unroll
        for (int ct = 0; ct < 4; ++ct)
            acc[rt][ct] = (floatx4){0.f, 0.f, 0.f, 0.f};

    // per-lane B-frag byte offset within staged half-chunk (swizzle is local)
    // local col lc = (cbt+ct)*16 + li ; off = lc*64 + (kg ^ ((lc>>1)&3))*16
    const int lc0   = cbt * 16 + li;
    const int bfoff = lc0 * 64 + ((kg ^ ((lc0 >> 1) & 3)) * 16);

    // ---- K-loop: 5 macro-groups x 5 super-steps x 2 phases (t = 0..49)
    for (int mg = 0; mg < 5; ++mg) {
        // x for n-windows g10 = 2mg (phases t%10 in 0..4) and 2mg+1 (5..9):
        // lane needs x[row][4*g10 + kg]
        half2v xs[2][4];
#pragma unroll
        for (int w = 0; w < 2; ++w)
#pragma unroll
            for (int rt = 0; rt < 4; ++rt) {
                _Float16 xv = xlds[(rowb + rt * 16) * XSTR + (2 * mg + w) * 4 + kg];
                xs[w][rt] = (half2v){xv, xv};
            }

#pragma unroll
        for (int ss5 = 0; ss5 < 5; ++ss5) {
            const int sstep = mg * 5 + ss5;
            // stage next super-chunk (t = 2*sstep+2, 2*sstep+3)
            if (sstep + 1 < NSUPER) {
                const char* src0 = (const char*)Wh + ch * HALF0_BYTES
                                 + (size_t)(2 * sstep + 2) * CHUNK_BYTES;
                unsigned char* dst0 = bsm + ((sstep + 1) & 1) * (2 * HALF0_BYTES);
                for (int q = 0; q < 2; ++q)
                    for (int u = wave; u * 1024 < half_bytes; u += 4) {
                        int off = u * 1024 + lane * 16;
                        if (off < half_bytes)
                            __builtin_amdgcn_global_load_lds(
                                (const __attribute__((address_space(1))) unsigned int*)
                                    (src0 + (size_t)q * CHUNK_BYTES + off),
                                (__attribute__((address_space(3))) unsigned int*)
                                    (dst0 + q * HALF0_BYTES + off),
                                16, 0, 0);
                    }
            }
            const unsigned char* cbuf = bsm + (sstep & 1) * (2 * HALF0_BYTES);

#pragma unroll
            for (int h = 0; h < 2; ++h) {
                const int t  = 2 * sstep + h;        // global step, compile-time shape
                const int p  = t % 5;                // y-group (uniform!)
                const int w  = (t / 5) & 1;          // x-window within macro-group
                const unsigned char* chunk = cbuf + h * HALF0_BYTES;

                half8 bf[4];
#pragma unroll
                for (int ct = 0; ct < 4; ++ct)
                    if (ct < nt)
                        bf[ct] = *(const half8*)(chunk + bfoff + ct * 1024);

                half8 af[4];
#pragma unroll
                for (int rt = 0; rt < 4; ++rt) {
                    half8 xsp = __builtin_shufflevector(xs[w][rt], xs[w][rt],
                                                        0, 1, 0, 1, 0, 1, 0, 1);
                    af[rt] = xsp * yr[rt][p];
                }

#pragma unroll
                for (int ct = 0; ct < 4; ++ct)
                    if (ct < nt)
#pragma unroll
                        for (int rt = 0; rt < 4; ++rt)
                            acc[rt][ct] = __builtin_amdgcn_mfma_f32_16x16x32_f16(
                                af[rt], bf[ct], acc[rt][ct], 0, 0, 0);
            }
            __syncthreads();   // one drain per super-step (25 total)
        }
    }

    // ---- epilogue: C/D layout col = lane&15, row = (lane>>4)*4 + reg  [m89]
#pragma unroll
    for (int rt = 0; rt < 4; ++rt) {
#pragma unroll
        for (int ct = 0; ct < 4; ++ct) {
            if (ct >= nt) continue;
            int gcol = ch * 112 + (cbt + ct) * 16 + li;
            if (gcol < OOv) {
#pragma unroll
                for (int r4 = 0; r4 < 4; ++r4) {
                    long grow = blockbase + rowhalf * 64 + rt * 16 + kg * 4 + r4;
                    Out[grow * OOv + gcol] = acc[rt][ct][r4];
                }
            }
        }
    }
}

extern "C" void kernel_launch(void* const* d_in, const int* in_sizes, int n_in,
                              void* d_out, int out_size, void* d_ws, size_t ws_size,
                              hipStream_t stream) {
    (void)in_sizes; (void)n_in; (void)out_size; (void)ws_size;
    const float* X = (const float*)d_in[0];
    const float* Y = (const float*)d_in[1];
    const float* W = (const float*)d_in[2];
    float* Out = (float*)d_out;
    unsigned short* Wh = (unsigned short*)d_ws;   // 665,600 B scratch (as before)

    wb_convert_kernel<<<1300, 256, 0, stream>>>(W, Wh);
    cin_mfma_kernel<<<1024, 256, 0, stream>>>(X, Y, Wh, Out);
}

// Round 6
// 130.066 us; speedup vs baseline: 1.0497x; 1.0497x over previous
//
#include <hip/hip_runtime.h>
#include <hip/hip_fp16.h>

// Problem constants
#define OOv   200
#define KKv   1600
#define OPAD  208              // 13 col-tiles of 16
#define NSTEPS 50              // K=32 MFMA steps
#define NSUPER 25              // BK=64 super-steps
#define CHUNK_BYTES 13312      // one K=32 chunk of W-fp16 (208*4 slots * 16B)
#define SUPER_BYTES 26624      // two chunks
#define XSTR 40                // halfs per x row in LDS
#define YSTR 40                // halfs per y row in LDS

typedef _Float16 half8  __attribute__((ext_vector_type(8)));
typedef _Float16 half2v __attribute__((ext_vector_type(2)));
typedef __attribute__((ext_vector_type(4))) float floatx4;

// ---------------------------------------------------------------------------
// Pre-kernel: W [200][1600] fp32 -> Wh fp16, PERMUTED-K chunk-major, swizzled.
// Wh idx = t*6656 + slot*8 + j ; slot = o*4 + (kg ^ ((o>>1)&3)) ;
// k_orig = (4*(t/5) + kg)*40 + 8*(t%5) + j
// => at step t, every lane's y-window is m in [8*(t%5), +8) (uniform) and
//    x-index n = 4*(t/5)+kg (changes once per 5 steps).  [validated R5]
// ---------------------------------------------------------------------------
__global__ void wb_convert_kernel(const float* __restrict__ W,
                                  unsigned short* __restrict__ Wh) {
    int idx = blockIdx.x * 256 + threadIdx.x;
    if (idx >= NSTEPS * OPAD * 32) return;      // 332800
    int j    = idx & 7;
    int slot = (idx >> 3) % (OPAD * 4);
    int t    = (idx >> 3) / (OPAD * 4);
    int o    = slot >> 2;
    int kgs  = slot & 3;
    int kg   = kgs ^ ((o >> 1) & 3);
    int k    = (4 * (t / 5) + kg) * 40 + 8 * (t % 5) + j;
    float v  = (o < OOv) ? W[o * KKv + k] : 0.0f;
    union { _Float16 h; unsigned short u; } cv; cv.h = (_Float16)v;
    Wh[idx] = cv.u;
}

// ---------------------------------------------------------------------------
// Main kernel: 1024 blocks x 512 thr. Block = 64 rows x 208 cols (full width:
// x/y fetched once, full-chunk staging shared by all 8 waves).
// Waves: rowgrp = wave&1 (rt=2: rows rowgrp*32 + rt*16 + li),
//        colgrp = wave>>1 (tiles {4,3,3,3}).
// acc 32 + y-in-regs 40 -> <=128 regs -> 4 waves/SIMD, 2 blocks/CU.
// K-loop LDS = B-frags only (y in regs via K-permutation; x 4 u16/macro-group).
// ---------------------------------------------------------------------------
__global__ __launch_bounds__(512, 4) void cin_mfma_kernel(
        const float* __restrict__ X, const float* __restrict__ Y,
        const unsigned short* __restrict__ Wh, float* __restrict__ Out) {
    __shared__ __align__(16) unsigned char bsm[2 * SUPER_BYTES];   // 53248
    __shared__ __align__(16) _Float16 xlds[64 * XSTR];             //  5120
    __shared__ __align__(16) _Float16 ylds[64 * YSTR];             //  5120

    const int tid    = threadIdx.x;
    const int wave   = tid >> 6;
    const int lane   = tid & 63;
    const int li     = lane & 15;
    const int kg     = lane >> 4;
    const int rowgrp = wave & 1;
    const int colgrp = wave >> 1;

    static const int nt_t[4]  = {4, 3, 3, 3};
    static const int cbt_t[4] = {0, 4, 7, 10};
    const int nt  = nt_t[colgrp];
    const int cbt = cbt_t[colgrp];
    const long blockbase = (long)blockIdx.x * 64;

    // ---- prologue: stage x,y (64 rows x 40) as fp16 into LDS
    const float* xg = X + blockbase * 40;
    const float* yg = Y + blockbase * 40;
    for (int i = tid; i < 640; i += 512) {       // 640 float4s = 2560 floats
        int r  = i / 10;
        int c4 = (i % 10) * 4;                   // 40 % 4 == 0: row-aligned
        floatx4 vx = *(const floatx4*)(xg + i * 4);
        floatx4 vy = *(const floatx4*)(yg + i * 4);
        union { half2v h[2]; unsigned long long u; } px, py;
        px.h[0] = (half2v){(_Float16)vx.x, (_Float16)vx.y};
        px.h[1] = (half2v){(_Float16)vx.z, (_Float16)vx.w};
        py.h[0] = (half2v){(_Float16)vy.x, (_Float16)vy.y};
        py.h[1] = (half2v){(_Float16)vy.z, (_Float16)vy.w};
        *(unsigned long long*)(xlds + r * XSTR + c4) = px.u;
        *(unsigned long long*)(ylds + r * YSTR + c4) = py.u;
    }
    // stage super-chunk 0 (26 KB over 8 waves)
    for (int u = wave; u < 26; u += 8) {
        int off = u * 1024 + lane * 16;
        __builtin_amdgcn_global_load_lds(
            (const __attribute__((address_space(1))) unsigned int*)((const char*)Wh + off),
            (__attribute__((address_space(3))) unsigned int*)(bsm + off),
            16, 0, 0);
    }
    __syncthreads();

    // ---- y rows into registers: yr[rt][p] = y[row][8p .. 8p+7]
    half8 yr[2][5];
#pragma unroll
    for (int rt = 0; rt < 2; ++rt) {
        int row = rowgrp * 32 + rt * 16 + li;
#pragma unroll
        for (int p = 0; p < 5; ++p)
            yr[rt][p] = *(const half8*)(ylds + row * YSTR + p * 8);
    }

    floatx4 acc[2][4];
#pragma unroll
    for (int rt = 0; rt < 2; ++rt)
#pragma unroll
        for (int ct = 0; ct < 4; ++ct)
            acc[rt][ct] = (floatx4){0.f, 0.f, 0.f, 0.f};

    // per-lane B-frag byte offset (swizzle term indep. of ct: (lc>>1)&3 == (li>>1)&3)
    const int bfoff = (cbt * 16 + li) * 64 + ((kg ^ ((li >> 1) & 3)) * 16);

    // ---- K-loop: 5 macro-groups x 5 super-steps x 2 phases (t = 0..49)
    for (int mg = 0; mg < 5; ++mg) {
        // x for the two n-windows of this macro-group: n = 4*(2mg+w) + kg
        half2v xs[2][2];
#pragma unroll
        for (int w = 0; w < 2; ++w)
#pragma unroll
            for (int rt = 0; rt < 2; ++rt) {
                _Float16 xv = xlds[(rowgrp * 32 + rt * 16 + li) * XSTR
                                   + (2 * mg + w) * 4 + kg];
                xs[w][rt] = (half2v){xv, xv};
            }

#pragma unroll
        for (int ss5 = 0; ss5 < 5; ++ss5) {
            const int sstep = mg * 5 + ss5;
            // stage next super-chunk (issued a full super-step before its drain)
            if (sstep + 1 < NSUPER) {
                const char* src = (const char*)Wh + (size_t)(sstep + 1) * SUPER_BYTES;
                unsigned char* dst = bsm + ((sstep + 1) & 1) * SUPER_BYTES;
                for (int u = wave; u < 26; u += 8) {
                    int off = u * 1024 + lane * 16;
                    __builtin_amdgcn_global_load_lds(
                        (const __attribute__((address_space(1))) unsigned int*)(src + off),
                        (__attribute__((address_space(3))) unsigned int*)(dst + off),
                        16, 0, 0);
                }
            }
            const unsigned char* cbuf = bsm + (sstep & 1) * SUPER_BYTES;

#pragma unroll
            for (int h = 0; h < 2; ++h) {
                const int t = 2 * sstep + h;         // compile-time shape per phase
                const int p = t % 5;                 // y-window (uniform across lanes)
                const int w = (t / 5) & 1;           // x-window within macro-group
                const unsigned char* chunk = cbuf + h * CHUNK_BYTES;

                half8 bf[4];
#pragma unroll
                for (int ct = 0; ct < 4; ++ct)
                    if (ct < nt)
                        bf[ct] = *(const half8*)(chunk + bfoff + ct * 1024);

                half8 af[2];
#pragma unroll
                for (int rt = 0; rt < 2; ++rt) {
                    half8 xsp = __builtin_shufflevector(xs[w][rt], xs[w][rt],
                                                        0, 1, 0, 1, 0, 1, 0, 1);
                    af[rt] = xsp * yr[rt][p];
                }

#pragma unroll
                for (int ct = 0; ct < 4; ++ct)
                    if (ct < nt)
#pragma unroll
                        for (int rt = 0; rt < 2; ++rt)
                            acc[rt][ct] = __builtin_amdgcn_mfma_f32_16x16x32_f16(
                                af[rt], bf[ct], acc[rt][ct], 0, 0, 0);
            }
            __syncthreads();   // one drain per super-step (25 total)
        }
    }

    // ---- epilogue: C/D layout col = lane&15, row = (lane>>4)*4 + reg  [m89]
#pragma unroll
    for (int rt = 0; rt < 2; ++rt) {
#pragma unroll
        for (int ct = 0; ct < 4; ++ct) {
            if (ct >= nt) continue;
            int gcol = (cbt + ct) * 16 + li;
            if (gcol < OOv) {
#pragma unroll
                for (int r4 = 0; r4 < 4; ++r4) {
                    long grow = blockbase + rowgrp * 32 + rt * 16 + kg * 4 + r4;
                    Out[grow * OOv + gcol] = acc[rt][ct][r4];
                }
            }
        }
    }
}

extern "C" void kernel_launch(void* const* d_in, const int* in_sizes, int n_in,
                              void* d_out, int out_size, void* d_ws, size_t ws_size,
                              hipStream_t stream) {
    (void)in_sizes; (void)n_in; (void)out_size; (void)ws_size;
    const float* X = (const float*)d_in[0];
    const float* Y = (const float*)d_in[1];
    const float* W = (const float*)d_in[2];
    float* Out = (float*)d_out;
    unsigned short* Wh = (unsigned short*)d_ws;   // 665,600 B scratch

    wb_convert_kernel<<<1300, 256, 0, stream>>>(W, Wh);
    cin_mfma_kernel<<<1024, 512, 0, stream>>>(X, Y, Wh, Out);
}